// Round 5
// baseline (430.074 us; speedup 1.0000x reference)
//
#include <hip/hip_runtime.h>
#include <hip/hip_bf16.h>
#include <math.h>

#define D_EMB 512
#define HD 64
#define BB 8
#define NN 2048
#define MROWS (BB*NN)   // 16384

typedef short short8  __attribute__((ext_vector_type(8)));
typedef short short4v __attribute__((ext_vector_type(4)));
typedef float f32x4   __attribute__((ext_vector_type(4)));

// scale(1/sqrt(512)) * log2(e): folded into Qb so P = exp2(S') directly
#define QSCALE 0.063758708f

__device__ __forceinline__ short f2bf(float x){
    unsigned u = __float_as_uint(x);
    unsigned r = (u + 0x7fffu + ((u >> 16) & 1u)) >> 16;
    return (short)r;
}
__device__ __forceinline__ float bf2f(short b){
    return __uint_as_float(((unsigned)(unsigned short)b) << 16);
}
__device__ __forceinline__ unsigned pkbf(float a, float b){
    __hip_bfloat162 h = __float22bfloat162_rn(make_float2(a, b));
    unsigned u; __builtin_memcpy(&u, &h, 4); return u;
}

// ================ K1: fused W-convert (to LDS, frag order) + projection =====
// 512 blocks x 256 thr (2 blocks/CU at 64 KB LDS). 3072 wave-units of 16 rows;
// waves 0,1 of each block take 2 units, waves 2,3 take 1 (per-CU balanced).
__global__ __launch_bounds__(256)
void proj_fused(const float* __restrict__ Xq, const float* __restrict__ Xk,
                const float* __restrict__ Xv, const float* __restrict__ W,
                short* __restrict__ Qb, short* __restrict__ Kb,
                short* __restrict__ Vt, unsigned* __restrict__ cnt)
{
    __shared__ short sWt[16*4*64*8];   // 64 KB, B-frag order [c16][t][lane][j]
    const int tid = threadIdx.x, lane = tid & 63;
    const int lc = lane & 15, quad = lane >> 4, w = tid >> 6;
    const int bl = blockIdx.x;

    // zero attention finalize counters (any 1024 ints; blocks 0..3)
    if (bl < 4){ int idx = bl*256 + tid; if (idx < 1024) cnt[idx] = 0u; }

    // ---- phase A: W[k][n] f32 -> sWt frag order (bf16)
#pragma unroll 4
    for (int p = 0; p < 32; ++p){
        const int i4 = tid + p*256;          // 8192 float4 of W
        const int k  = i4 >> 4;
        const int nb = (i4 & 15) * 4;
        float4 v = *(const float4*)(W + k*HD + nb);
        const int base = (((k >> 5)*4 + (nb >> 4))*64 + ((k >> 3) & 3)*16 + (nb & 15))*8 + (k & 7);
        sWt[base]      = f2bf(v.x);
        sWt[base + 8]  = f2bf(v.y);
        sWt[base + 16] = f2bf(v.z);
        sWt[base + 24] = f2bf(v.w);
    }
    __syncthreads();

    // ---- phase B: projection units
    const int nu = (w < 2) ? 2 : 1;
    int units[2];
    units[0] = bl*4 + w;                 // 0..2047
    units[1] = 2048 + bl*2 + w;          // only valid for w<2 -> 2048..4095? no: bl*2+w covers 0..1023

    for (int uu = 0; uu < nu; ++uu){
        const int unit = units[uu];
        const int tensor = unit >> 10;           // 0=Q 1=K 2=V
        const int rloc = (unit & 1023) * 16;
        const float* X = (tensor == 0) ? Xq : (tensor == 1 ? Xk : Xv);
        const float* xbase = X + (size_t)(rloc + lc)*D_EMB + quad*8;

        f32x4 acc[4];
#pragma unroll
        for (int t = 0; t < 4; ++t)
#pragma unroll
            for (int r = 0; r < 4; ++r) acc[t][r] = 0.f;

        float4 xa[4][2];
#pragma unroll
        for (int p = 0; p < 4; ++p){
            xa[p][0] = *(const float4*)(xbase + p*32);
            xa[p][1] = *(const float4*)(xbase + p*32 + 4);
        }
#pragma unroll
        for (int c16 = 0; c16 < 16; ++c16){
            float4 f0 = xa[c16 & 3][0], f1 = xa[c16 & 3][1];
            if (c16 < 12){
                xa[c16 & 3][0] = *(const float4*)(xbase + (c16+4)*32);
                xa[c16 & 3][1] = *(const float4*)(xbase + (c16+4)*32 + 4);
            }
            union { short8 s8; unsigned u[4]; } a;
            a.u[0] = pkbf(f0.x, f0.y); a.u[1] = pkbf(f0.z, f0.w);
            a.u[2] = pkbf(f1.x, f1.y); a.u[3] = pkbf(f1.z, f1.w);
#pragma unroll
            for (int t = 0; t < 4; ++t){
                short8 bf = *(const short8*)&sWt[((c16*4 + t)*64 + lane)*8];
                acc[t] = __builtin_amdgcn_mfma_f32_16x16x32_bf16(a.s8, bf, acc[t], 0,0,0);
            }
        }

        if (tensor == 0){
#pragma unroll
            for (int t = 0; t < 4; ++t)
#pragma unroll
                for (int r = 0; r < 4; ++r)
                    Qb[(size_t)(rloc + quad*4 + r)*HD + t*16 + lc] = f2bf(acc[t][r] * QSCALE);
        } else if (tensor == 1){
#pragma unroll
            for (int t = 0; t < 4; ++t)
#pragma unroll
                for (int r = 0; r < 4; ++r)
                    Kb[(size_t)(rloc + quad*4 + r)*HD + t*16 + lc] = f2bf(acc[t][r]);
        } else {
            const int bb = rloc >> 11;
            const int n0 = (rloc & 2047) + quad*4;
#pragma unroll
            for (int t = 0; t < 4; ++t){
                union { short4v s4; unsigned u[2]; } p;
                p.u[0] = pkbf(acc[t][0], acc[t][1]);
                p.u[1] = pkbf(acc[t][2], acc[t][3]);
                *(short4v*)(Vt + ((size_t)(bb*HD + t*16 + lc))*NN + n0) = p.s4;
            }
        }
    }
}

// ================ K2: split-K flash attention + inline last-done combine ====
template<int CSH>
__global__ __launch_bounds__(256)
void attn_part(const short* __restrict__ Qb, const short* __restrict__ Kb,
               const short* __restrict__ Vt, const unsigned char* __restrict__ pad,
               const int* __restrict__ mflag, float* __restrict__ out,
               float* __restrict__ Lp, short* __restrict__ Op,
               unsigned* __restrict__ cnt)
{
    constexpr int G   = 1 << CSH;
    constexpr int NG  = 128 / G;
    constexpr int UPB = 64 * (NG + 1);
    constexpr int PPB = G * (NG - 1) * (NG + 2) / 2;

    __shared__ short sP[4][16][80];
    const int tid = threadIdx.x, lane = tid & 63, lc = lane & 15, quad = lane >> 4, w = tid >> 6;
    const int unit = blockIdx.x * 4 + w;
    const int b = unit / UPB;
    int rem = unit - b * UPB;
    int g = 0, off = 0;
    while (rem >= off + G * (g + 1)) { off += G * (g + 1); ++g; }
    const int rr = rem - off;
    const int C = g + 1;
    const int s = G * g + rr / C;
    const int c = rr - (rr / C) * C;

    const bool causal = (mflag[0] != 0);
    const int q0 = s * 16;
    const int T = causal ? ((s >> 2) + 1) : (NN / 64);
    const int qq = (T + C - 1) / C;
    const int t0 = c * qq;
    const int t1 = min(t0 + qq, T);
    const unsigned char* padb = pad + (size_t)b * NN;
    const size_t bNN = (size_t)b * NN;

    const short* qrow = Qb + (bNN + q0 + lc) * HD;
    const short8 qf0 = *(const short8*)(qrow + quad * 8);
    const short8 qf1 = *(const short8*)(qrow + 32 + quad * 8);

    f32x4 o[4];
#pragma unroll
    for (int t = 0; t < 4; ++t)
#pragma unroll
        for (int r = 0; r < 4; ++r) o[t][r] = 0.f;
    float lacc = 0.f;

    // preload K tile t0
    short8 kf0[4], kf1[4];
    {
        const int kk = t0 * 64;
#pragma unroll
        for (int t = 0; t < 4; ++t){
            const short* kr = Kb + (bNN + kk + t*16 + lc)*HD;
            kf0[t] = *(const short8*)(kr + quad*8);
            kf1[t] = *(const short8*)(kr + 32 + quad*8);
        }
    }

    for (int kt = t0; kt < t1; ++kt){
        const int k0 = kt * 64;
        // S^T = K Q^T
        f32x4 st[4];
#pragma unroll
        for (int t = 0; t < 4; ++t){
#pragma unroll
            for (int r = 0; r < 4; ++r) st[t][r] = 0.f;
            st[t] = __builtin_amdgcn_mfma_f32_16x16x32_bf16(kf0[t], qf0, st[t], 0,0,0);
            st[t] = __builtin_amdgcn_mfma_f32_16x16x32_bf16(kf1[t], qf1, st[t], 0,0,0);
        }
        // V for current tile (latency hidden behind exp/PV deps)
        short8 vf0[4], vf1[4];
#pragma unroll
        for (int t = 0; t < 4; ++t){
            const short* vr = Vt + ((size_t)b*HD + t*16 + lc)*NN + k0;
            vf0[t] = *(const short8*)(vr + quad*8);
            vf1[t] = *(const short8*)(vr + 32 + quad*8);
        }
        // prefetch K for next tile (overwrites kf after S-MFMAs consumed them)
        if (kt + 1 < t1){
            const int kk = k0 + 64;
#pragma unroll
            for (int t = 0; t < 4; ++t){
                const short* kr = Kb + (bNN + kk + t*16 + lc)*HD;
                kf0[t] = *(const short8*)(kr + quad*8);
                kf1[t] = *(const short8*)(kr + 32 + quad*8);
            }
        }

        const bool dg = causal && (kt == T - 1);
        const int thr = q0 + lc - k0;            // keep iff n_local <= thr
#pragma unroll
        for (int t = 0; t < 4; ++t){
            uchar4 pb = *(const uchar4*)(padb + k0 + t*16 + quad*4);
            float e[4];
#pragma unroll
            for (int r = 0; r < 4; ++r){
                float v = st[t][r];
                const unsigned char pr = (r==0)?pb.x:(r==1)?pb.y:(r==2)?pb.z:pb.w;
                const int nloc = t*16 + quad*4 + r;
                if (pr || (dg && nloc > thr)) v = -INFINITY;
                e[r] = exp2f(v);
                lacc += e[r];
            }
            union { short4v s4; unsigned u[2]; } pk;
            pk.u[0] = pkbf(e[0], e[1]);
            pk.u[1] = pkbf(e[2], e[3]);
            *(short4v*)&sP[w][lc][t*16 + quad*4] = pk.s4;
        }
        const short8 pf0 = *(const short8*)&sP[w][lc][quad*8];
        const short8 pf1 = *(const short8*)&sP[w][lc][32 + quad*8];
#pragma unroll
        for (int t = 0; t < 4; ++t){
            o[t] = __builtin_amdgcn_mfma_f32_16x16x32_bf16(pf0, vf0[t], o[t], 0,0,0);
            o[t] = __builtin_amdgcn_mfma_f32_16x16x32_bf16(pf1, vf1[t], o[t], 0,0,0);
        }
    }

    // l across quads (same lc)
    lacc += __shfl_xor(lacc, 16);
    lacc += __shfl_xor(lacc, 32);

    if (C == 1){
        float linv[4];
#pragma unroll
        for (int r = 0; r < 4; ++r) linv[r] = 1.f / __shfl(lacc, quad*4 + r);
#pragma unroll
        for (int r = 0; r < 4; ++r){
            float* orow = out + (bNN + q0 + quad*4 + r)*HD;
#pragma unroll
            for (int t = 0; t < 4; ++t) orow[t*16 + lc] = o[t][r] * linv[r];
        }
    } else {
        const int base = G*(g-1)*(g+2)/2 + (s - G*g)*(1+g);
        const int pu0 = b*PPB + base;
        const int pu  = pu0 + c;
        short* op = Op + (size_t)pu * 1024;
#pragma unroll
        for (int t = 0; t < 4; ++t)
#pragma unroll
            for (int r = 0; r < 4; ++r)
                op[(quad*4 + r)*64 + t*16 + lc] = f2bf(o[t][r]);
        if (lane < 16) Lp[pu*16 + lane] = lacc;

        // release partials, then last-done wave combines
        __threadfence();
        unsigned old = 0;
        if (lane == 0) old = atomicAdd(&cnt[b*(128 - G) + (s - G)], 1u);
        old = __shfl(old, 0);
        if (old == (unsigned)(C - 1)){
            __threadfence();
#pragma unroll 2
            for (int row = 0; row < 16; ++row){
                float l = 0.f, acc = 0.f;
                for (int cc = 0; cc < C; ++cc){
                    l   += Lp[(pu0 + cc)*16 + row];
                    acc += bf2f(Op[((size_t)(pu0 + cc)*16 + row)*64 + lane]);
                }
                out[(bNN + q0 + row)*HD + lane] = acc / l;
            }
        }
    }
}

extern "C" void kernel_launch(void* const* d_in, const int* in_sizes, int n_in,
                              void* d_out, int out_size, void* d_ws, size_t ws_size,
                              hipStream_t stream) {
    const float* key_in   = (const float*)d_in[0];
    const float* query_in = (const float*)d_in[1];
    const float* value_in = (const float*)d_in[2];
    const unsigned char* pad = (const unsigned char*)d_in[3];
    const int* mflag      = (const int*)d_in[4];
    const float* Wk       = (const float*)d_in[5];
    // W_query / W_value unused — reference applies W_key to Q, K and V.

    short* Qb = (short*)d_ws;                    // 2 MiB (pre-scaled by QSCALE)
    short* Kb = Qb + (size_t)MROWS*HD;           // 2 MiB
    short* Vt = Kb + (size_t)MROWS*HD;           // 2 MiB, [b][d][n]
    unsigned* cnt = (unsigned*)(Vt + (size_t)MROWS*HD);   // 1024 ints
    float* Lp = (float*)(cnt + 1024);

    proj_fused<<<512, 256, 0, stream>>>(query_in, key_in, value_in, Wk, Qb, Kb, Vt, cnt);

    if (ws_size >= (size_t)15757312){
        // CSH=4: 4608 wave-units, partials 8*560
        short* Op = (short*)(Lp + 8*560*16);
        attn_part<4><<<1152, 256, 0, stream>>>(Qb, Kb, Vt, pad, mflag, (float*)d_out, Lp, Op, cnt);
    } else {
        // CSH=5: 2560 wave-units, 11.2 MB total (proven fit)
        short* Op = (short*)(Lp + 8*288*16);
        attn_part<5><<<640, 256, 0, stream>>>(Qb, Kb, Vt, pad, mflag, (float*)d_out, Lp, Op, cnt);
    }
}

// Round 6
// 313.190 us; speedup vs baseline: 1.3732x; 1.3732x over previous
//
#include <hip/hip_runtime.h>
#include <hip/hip_bf16.h>
#include <math.h>

#define D_EMB 512
#define HD 64
#define BB 8
#define NN 2048
#define MROWS (BB*NN)   // 16384

typedef short short8  __attribute__((ext_vector_type(8)));
typedef short short4v __attribute__((ext_vector_type(4)));
typedef float f32x4   __attribute__((ext_vector_type(4)));

// scale(1/sqrt(512)) * log2(e): folded into Qb so P = exp2(S') directly
#define QSCALE 0.063758708f

__device__ __forceinline__ short f2bf(float x){
    unsigned u = __float_as_uint(x);
    unsigned r = (u + 0x7fffu + ((u >> 16) & 1u)) >> 16;
    return (short)r;
}
__device__ __forceinline__ float bf2f(short b){
    return __uint_as_float(((unsigned)(unsigned short)b) << 16);
}
__device__ __forceinline__ unsigned pkbf(float a, float b){
    __hip_bfloat162 h = __float22bfloat162_rn(make_float2(a, b));
    unsigned u; __builtin_memcpy(&u, &h, 4); return u;
}
// async global->LDS, 16B per lane (global_load_lds_dwordx4)
__device__ __forceinline__ void gl16(const short* g, short* l){
    __builtin_amdgcn_global_load_lds(
        (const __attribute__((address_space(1))) unsigned*)g,
        (__attribute__((address_space(3))) unsigned*)l, 16, 0, 0);
}

// ---------------- Wt[n][k] (bf16) <- W[k][n] (f32)
__global__ __launch_bounds__(256)
void wt_kernel(const float* __restrict__ W, short* __restrict__ Wt){
    for (int idx = blockIdx.x * 256 + threadIdx.x; idx < D_EMB*HD; idx += 8*256){
        int k = idx >> 6, n = idx & 63;
        Wt[n*D_EMB + k] = f2bf(W[idx]);
    }
}

// ---------------- Projection. 16 rows/wave, MFMA, prefetch depth 8.
// Q: row-major, pre-scaled. K/V: tile-contiguous (64n x 64d = 8KB) with
// 16B-chunk XOR swizzle so attn's linear global_load_lds image gives
// conflict-free ds_read_b128 fragments.
__global__ __launch_bounds__(256)
void proj_kernel(const float* __restrict__ Xq, const float* __restrict__ Xk,
                 const float* __restrict__ Xv, const short* __restrict__ Wt,
                 short* __restrict__ Qb, short* __restrict__ Kb,
                 short* __restrict__ Vt)
{
    const int lane = threadIdx.x & 63;
    const int lc = lane & 15, quad = lane >> 4;
    const int wid = blockIdx.x * 4 + (threadIdx.x >> 6);
    const int m0 = wid * 16;
    const int tensor = m0 >> 14;             // 0=Q 1=K 2=V
    const int rloc = m0 & (MROWS - 1);
    const float* X = (tensor == 0) ? Xq : (tensor == 1 ? Xk : Xv);
    const float* xbase = X + (size_t)(rloc + lc)*D_EMB + quad*8;

    f32x4 acc[4];
#pragma unroll
    for (int t = 0; t < 4; ++t)
#pragma unroll
        for (int r = 0; r < 4; ++r) acc[t][r] = 0.f;

    float4 xa[8][2];
#pragma unroll
    for (int p = 0; p < 8; ++p){
        xa[p][0] = *(const float4*)(xbase + p*32);
        xa[p][1] = *(const float4*)(xbase + p*32 + 4);
    }
#pragma unroll
    for (int c16 = 0; c16 < 16; ++c16){
        float4 f0 = xa[c16 & 7][0], f1 = xa[c16 & 7][1];
        if (c16 < 8){
            xa[c16 & 7][0] = *(const float4*)(xbase + (c16+8)*32);
            xa[c16 & 7][1] = *(const float4*)(xbase + (c16+8)*32 + 4);
        }
        union { short8 s8; unsigned u[4]; } a;
        a.u[0] = pkbf(f0.x, f0.y); a.u[1] = pkbf(f0.z, f0.w);
        a.u[2] = pkbf(f1.x, f1.y); a.u[3] = pkbf(f1.z, f1.w);
        const int k0 = c16 * 32;
#pragma unroll
        for (int t = 0; t < 4; ++t){
            short8 bf = *(const short8*)(Wt + (size_t)(t*16 + lc)*D_EMB + k0 + quad*8);
            acc[t] = __builtin_amdgcn_mfma_f32_16x16x32_bf16(a.s8, bf, acc[t], 0,0,0);
        }
    }

    if (tensor == 0){
#pragma unroll
        for (int t = 0; t < 4; ++t)
#pragma unroll
            for (int r = 0; r < 4; ++r)
                Qb[(size_t)(rloc + quad*4 + r)*HD + t*16 + lc] = f2bf(acc[t][r] * QSCALE);
    } else if (tensor == 1){
        // K tile layout: tile=R>>6; off = nin*64 + ((d>>3)^(nin&7))*8 + (d&7)
#pragma unroll
        for (int t = 0; t < 4; ++t)
#pragma unroll
            for (int r = 0; r < 4; ++r){
                const int R = rloc + quad*4 + r;
                const int nin = R & 63;
                const int off = ((R >> 6) << 12) + nin*64
                              + ((((t << 1) | (lc >> 3)) ^ (nin & 7)) << 3) + (lc & 7);
                Kb[off] = f2bf(acc[t][r]);
            }
    } else {
        // V tile layout: tile=R>>6; off = d*64 + ((nin>>3)^(d&7))*8 + (nin&7)
#pragma unroll
        for (int t = 0; t < 4; ++t)
#pragma unroll
            for (int r = 0; r < 4; ++r){
                const int R = rloc + quad*4 + r;
                const int nin = R & 63;
                const int d = t*16 + lc;
                const int off = ((R >> 6) << 12) + d*64
                              + (((nin >> 3) ^ (lc & 7)) << 3) + (nin & 7);
                Vt[off] = f2bf(acc[t][r]);
            }
    }
}

// ---------------- Attention: block = (b, 64-row q-block j, k-chunk c).
// 4 waves share double-buffered global_load_lds-staged K/V tiles.
// C = ceil(T / (1<<SH-ish)) via group decode; separate combine (no atomics).
template<int SH>
__global__ __launch_bounds__(256)
void attn_part(const short* __restrict__ Qb, const short* __restrict__ Kb,
               const short* __restrict__ Vt, const unsigned char* __restrict__ pad,
               const int* __restrict__ mflag, float* __restrict__ out,
               float* __restrict__ Lp, short* __restrict__ Op)
{
    constexpr int M   = 1 << SH;
    constexpr int NG  = 32 / M;
    constexpr int UPB = M * NG * (NG + 1) / 2;
    constexpr int PPB = UPB - M;

    __shared__ short sK[2][4096];
    __shared__ short sV[2][4096];
    __shared__ short sP[4][16][80];

    const int tid = threadIdx.x, lane = tid & 63, lc = lane & 15, quad = lane >> 4, w = tid >> 6;
    const int unit = blockIdx.x;
    const int b = unit / UPB;
    const int rem = unit - b * UPB;
    int a = 0;
    while (rem >= (M * (a + 1) * (a + 2)) / 2) ++a;
    const int u = rem - M * a * (a + 1) / 2;
    const int C = a + 1;
    const int r = u / C, c = u - r * C;
    const int j = a * M + r;
    const int q0 = j * 64;

    const bool causal = (mflag[0] != 0);
    const int T = causal ? (j + 1) : 32;
    const int qq = (T + C - 1) / C;
    const int t0 = c * qq;
    const int t1 = min(t0 + qq, T);
    const int tb = b * 32;
    const unsigned char* padb = pad + (size_t)b * NN;

    const short* qrow = Qb + ((size_t)b * NN + q0 + w*16 + lc) * HD;
    const short8 qf0 = *(const short8*)(qrow + quad * 8);
    const short8 qf1 = *(const short8*)(qrow + 32 + quad * 8);

    f32x4 o[4];
#pragma unroll
    for (int t = 0; t < 4; ++t)
#pragma unroll
        for (int rr = 0; rr < 4; ++rr) o[t][rr] = 0.f;
    float lacc = 0.f;

    // stage tile t0 into buffer 0 (wave w copies its 2KB quarter of K and V)
    {
        const short* gk = Kb + ((size_t)(tb + t0) << 12) + w*1024 + lane*8;
        const short* gv = Vt + ((size_t)(tb + t0) << 12) + w*1024 + lane*8;
        short* lk = &sK[0][w*1024 + lane*8];
        short* lv = &sV[0][w*1024 + lane*8];
        gl16(gk, lk); gl16(gk + 512, lk + 512);
        gl16(gv, lv); gl16(gv + 512, lv + 512);
    }

    int buf = 0;
    const int sw = lc & 7;
    for (int kt = t0; kt < t1; ++kt, buf ^= 1){
        __syncthreads();                       // staging of buf complete; prev readers done
        if (kt + 1 < t1){
            const short* gk = Kb + ((size_t)(tb + kt + 1) << 12) + w*1024 + lane*8;
            const short* gv = Vt + ((size_t)(tb + kt + 1) << 12) + w*1024 + lane*8;
            short* lk = &sK[buf ^ 1][w*1024 + lane*8];
            short* lv = &sV[buf ^ 1][w*1024 + lane*8];
            gl16(gk, lk); gl16(gk + 512, lk + 512);
            gl16(gv, lv); gl16(gv + 512, lv + 512);
        }
        const int k0 = kt * 64;
        // fragments from LDS (swizzle-corrected, conflict-free b128)
        short8 kf0[4], kf1[4], vf0[4], vf1[4];
#pragma unroll
        for (int t = 0; t < 4; ++t){
            const int row = (t*16 + lc) * 64;
            kf0[t] = *(const short8*)&sK[buf][row + ((quad ^ sw) << 3)];
            kf1[t] = *(const short8*)&sK[buf][row + (((quad + 4) ^ sw) << 3)];
            vf0[t] = *(const short8*)&sV[buf][row + ((quad ^ sw) << 3)];
            vf1[t] = *(const short8*)&sV[buf][row + (((quad + 4) ^ sw) << 3)];
        }
        // S^T = K Q^T : D[n][q], n = t*16+quad*4+rr, q = w*16+lc
        f32x4 st[4];
#pragma unroll
        for (int t = 0; t < 4; ++t){
#pragma unroll
            for (int rr = 0; rr < 4; ++rr) st[t][rr] = 0.f;
            st[t] = __builtin_amdgcn_mfma_f32_16x16x32_bf16(kf0[t], qf0, st[t], 0,0,0);
            st[t] = __builtin_amdgcn_mfma_f32_16x16x32_bf16(kf1[t], qf1, st[t], 0,0,0);
        }
        const bool dg = causal && (kt == j);
        const int thr = q0 + w*16 + lc - k0;   // keep iff n_local <= thr
#pragma unroll
        for (int t = 0; t < 4; ++t){
            uchar4 pb = *(const uchar4*)(padb + k0 + t*16 + quad*4);
            float e[4];
#pragma unroll
            for (int rr = 0; rr < 4; ++rr){
                float v = st[t][rr];
                const unsigned char pr = (rr==0)?pb.x:(rr==1)?pb.y:(rr==2)?pb.z:pb.w;
                const int nloc = t*16 + quad*4 + rr;
                if (pr || (dg && nloc > thr)) v = -INFINITY;
                e[rr] = exp2f(v);
                lacc += e[rr];
            }
            union { short4v s4; unsigned uu[2]; } pk;
            pk.uu[0] = pkbf(e[0], e[1]);
            pk.uu[1] = pkbf(e[2], e[3]);
            *(short4v*)&sP[w][lc][t*16 + quad*4] = pk.s4;
        }
        const short8 pf0 = *(const short8*)&sP[w][lc][quad*8];
        const short8 pf1 = *(const short8*)&sP[w][lc][32 + quad*8];
#pragma unroll
        for (int t = 0; t < 4; ++t){
            o[t] = __builtin_amdgcn_mfma_f32_16x16x32_bf16(pf0, vf0[t], o[t], 0,0,0);
            o[t] = __builtin_amdgcn_mfma_f32_16x16x32_bf16(pf1, vf1[t], o[t], 0,0,0);
        }
    }

    lacc += __shfl_xor(lacc, 16);
    lacc += __shfl_xor(lacc, 32);

    if (C == 1){
        float linv[4];
#pragma unroll
        for (int rr = 0; rr < 4; ++rr) linv[rr] = 1.f / __shfl(lacc, quad*4 + rr);
#pragma unroll
        for (int rr = 0; rr < 4; ++rr){
            float* orow = out + ((size_t)b*NN + q0 + w*16 + quad*4 + rr)*HD;
#pragma unroll
            for (int t = 0; t < 4; ++t) orow[t*16 + lc] = o[t][rr] * linv[rr];
        }
    } else {
        const int pu = b*PPB + (M*a*(a+1)/2 - M) + r*C + c;
        short* op = Op + (size_t)pu * 4096;
#pragma unroll
        for (int t = 0; t < 4; ++t)
#pragma unroll
            for (int rr = 0; rr < 4; ++rr)
                op[(w*16 + quad*4 + rr)*64 + t*16 + lc] = f2bf(o[t][rr]);
        if (lane < 16) Lp[pu*64 + w*16 + lane] = lacc;
    }
}

// ---------------- Combine (separate kernel; max-free -> plain sums)
template<int SH>
__global__ __launch_bounds__(256)
void attn_combine(const float* __restrict__ Lp, const short* __restrict__ Op,
                  float* __restrict__ out)
{
    constexpr int M    = 1 << SH;
    constexpr int UPB  = M * (32/M) * (32/M + 1) / 2;
    constexpr int PPB  = UPB - M;
    constexpr int NSTR = 32 - M;
    const int tid = threadIdx.x, lane = tid & 63, w = tid >> 6;
    const int unit = blockIdx.x * 4 + w;
    const int b = unit / NSTR;
    const int j = M + (unit - b * NSTR);
    const int a = j >> SH;
    const int C = a + 1;
    const int r = j - a * M;
    const int pu0 = b*PPB + (M*a*(a+1)/2 - M) + r*C;
    const int q0 = j * 64;

#pragma unroll 4
    for (int row = 0; row < 64; ++row){
        float l = 0.f, acc = 0.f;
        for (int cc = 0; cc < C; ++cc){
            l   += Lp[(pu0 + cc)*64 + row];
            acc += bf2f(Op[(size_t)(pu0 + cc)*4096 + row*64 + lane]);
        }
        out[((size_t)b*NN + q0 + row)*HD + lane] = acc / l;
    }
}

extern "C" void kernel_launch(void* const* d_in, const int* in_sizes, int n_in,
                              void* d_out, int out_size, void* d_ws, size_t ws_size,
                              hipStream_t stream) {
    const float* key_in   = (const float*)d_in[0];
    const float* query_in = (const float*)d_in[1];
    const float* value_in = (const float*)d_in[2];
    const unsigned char* pad = (const unsigned char*)d_in[3];
    const int* mflag      = (const int*)d_in[4];
    const float* Wk       = (const float*)d_in[5];
    // W_query / W_value unused — reference applies W_key to Q, K and V.

    short* Qb = (short*)d_ws;                    // 2 MiB (pre-scaled by QSCALE)
    short* Kb = Qb + (size_t)MROWS*HD;           // 2 MiB, swizzled tiles
    short* Vt = Kb + (size_t)MROWS*HD;           // 2 MiB, swizzled tiles [d][n]
    short* Wt = Vt + (size_t)MROWS*HD;           // 64 KiB
    float* Lp = (float*)(Wt + D_EMB*HD);

    wt_kernel<<<8, 256, 0, stream>>>(Wk, Wt);
    proj_kernel<<<768, 256, 0, stream>>>(query_in, key_in, value_in, Wt, Qb, Kb, Vt);

    if (ws_size >= (size_t)15818752){
        // SH=2: 1152 blocks, <=4 tiles/block; Lp 1120*64 f32, Op 1120*4096 bf16
        short* Op = (short*)(Lp + 1120*64);
        attn_part<2><<<1152, 256, 0, stream>>>(Qb, Kb, Vt, pad, mflag, (float*)d_out, Lp, Op);
        attn_combine<2><<<56, 256, 0, stream>>>(Lp, Op, (float*)d_out);
    } else {
        // SH=3: 640 blocks, <=8 tiles/block; total 11.2 MB (proven fit)
        short* Op = (short*)(Lp + 576*64);
        attn_part<3><<<640, 256, 0, stream>>>(Qb, Kb, Vt, pad, mflag, (float*)d_out, Lp, Op);
        attn_combine<3><<<48, 256, 0, stream>>>(Lp, Op, (float*)d_out);
    }
}

// Round 7
// 172.765 us; speedup vs baseline: 2.4893x; 1.8128x over previous
//
#include <hip/hip_runtime.h>
#include <hip/hip_bf16.h>
#include <math.h>

#define D_EMB 512
#define HD 64
#define BB 8
#define NN 2048
#define MROWS (BB*NN)   // 16384

typedef short short8  __attribute__((ext_vector_type(8)));
typedef short short4v __attribute__((ext_vector_type(4)));
typedef float f32x4   __attribute__((ext_vector_type(4)));

// scale(1/sqrt(512)) * log2(e): folded into Qb so P = exp2(S') directly
#define QSCALE 0.063758708f

__device__ __forceinline__ short f2bf(float x){
    unsigned u = __float_as_uint(x);
    unsigned r = (u + 0x7fffu + ((u >> 16) & 1u)) >> 16;
    return (short)r;
}
__device__ __forceinline__ float bf2f(short b){
    return __uint_as_float(((unsigned)(unsigned short)b) << 16);
}
__device__ __forceinline__ unsigned pkbf(float a, float b){
    __hip_bfloat162 h = __float22bfloat162_rn(make_float2(a, b));
    unsigned u; __builtin_memcpy(&u, &h, 4); return u;
}
// async global->LDS, 16B per lane (global_load_lds_dwordx4)
__device__ __forceinline__ void gl16(const short* g, short* l){
    __builtin_amdgcn_global_load_lds(
        (const __attribute__((address_space(1))) unsigned*)g,
        (__attribute__((address_space(3))) unsigned*)l, 16, 0, 0);
}

// ---------------- Wtf: W[k][n] f32 -> bf16 in MFMA B-frag order
// off = ((c16*4 + t)*64 + lane)*8 + j  with c16=k>>5, t=n>>4,
// lane=((k>>3)&3)*16 + (n&15), j=k&7   (verified in R5 proj_fused phase A)
__global__ __launch_bounds__(256)
void wt_kernel(const float* __restrict__ W, short* __restrict__ Wtf){
    for (int idx = blockIdx.x * 256 + threadIdx.x; idx < D_EMB*HD; idx += 8*256){
        int k = idx >> 6, n = idx & 63;
        int off = (((k >> 5)*4 + (n >> 4))*64 + ((k >> 3) & 3)*16 + (n & 15))*8 + (k & 7);
        Wtf[off] = f2bf(W[idx]);
    }
}

// ---------------- Projection. 16 rows/wave, MFMA, 8-deep X prefetch (kept in
// regs via launch_bounds(256,2) -> 256-VGPR budget). Wt staged to LDS once per
// block in frag order; fragment reads are contiguous ds_read_b128.
// Q: row-major pre-scaled. K/V: tile-contiguous XOR-swizzled for attn staging.
__global__ __launch_bounds__(256, 2)
void proj_kernel(const float* __restrict__ Xq, const float* __restrict__ Xk,
                 const float* __restrict__ Xv, const short* __restrict__ Wtf,
                 short* __restrict__ Qb, short* __restrict__ Kb,
                 short* __restrict__ Vt)
{
    __shared__ short sWt[D_EMB*HD];   // 64 KB, frag order [c16][t][lane][8]
    const int tid = threadIdx.x;
    const int lane = tid & 63;
    const int lc = lane & 15, quad = lane >> 4;

    // linear 64 KB copy global -> LDS (wave-uniform base + lane*16)
#pragma unroll
    for (int p = 0; p < 16; ++p)
        gl16(Wtf + p*2048 + tid*8, &sWt[p*2048 + tid*8]);

    const int wid = blockIdx.x * 4 + (tid >> 6);
    const int m0 = wid * 16;
    const int tensor = m0 >> 14;             // 0=Q 1=K 2=V
    const int rloc = m0 & (MROWS - 1);
    const float* X = (tensor == 0) ? Xq : (tensor == 1 ? Xk : Xv);
    const float* xbase = X + (size_t)(rloc + lc)*D_EMB + quad*8;

    f32x4 acc[4];
#pragma unroll
    for (int t = 0; t < 4; ++t)
#pragma unroll
        for (int r = 0; r < 4; ++r) acc[t][r] = 0.f;

    float4 xa[8][2];
#pragma unroll
    for (int p = 0; p < 8; ++p){
        xa[p][0] = *(const float4*)(xbase + p*32);
        xa[p][1] = *(const float4*)(xbase + p*32 + 4);
    }
    __syncthreads();   // sWt staged (also drains the global_load_lds queue)

#pragma unroll
    for (int c16 = 0; c16 < 16; ++c16){
        float4 f0 = xa[c16 & 7][0], f1 = xa[c16 & 7][1];
        if (c16 < 8){
            xa[c16 & 7][0] = *(const float4*)(xbase + (c16+8)*32);
            xa[c16 & 7][1] = *(const float4*)(xbase + (c16+8)*32 + 4);
        }
        union { short8 s8; unsigned u[4]; } a;
        a.u[0] = pkbf(f0.x, f0.y); a.u[1] = pkbf(f0.z, f0.w);
        a.u[2] = pkbf(f1.x, f1.y); a.u[3] = pkbf(f1.z, f1.w);
#pragma unroll
        for (int t = 0; t < 4; ++t){
            short8 bf = *(const short8*)&sWt[((c16*4 + t)*64 + lane)*8];
            acc[t] = __builtin_amdgcn_mfma_f32_16x16x32_bf16(a.s8, bf, acc[t], 0,0,0);
        }
    }

    if (tensor == 0){
#pragma unroll
        for (int t = 0; t < 4; ++t)
#pragma unroll
            for (int r = 0; r < 4; ++r)
                Qb[(size_t)(rloc + quad*4 + r)*HD + t*16 + lc] = f2bf(acc[t][r] * QSCALE);
    } else if (tensor == 1){
        // K tile: tile=R>>6; off = nin*64 + ((d>>3)^(nin&7))*8 + (d&7)
#pragma unroll
        for (int t = 0; t < 4; ++t)
#pragma unroll
            for (int r = 0; r < 4; ++r){
                const int R = rloc + quad*4 + r;
                const int nin = R & 63;
                const int off = ((R >> 6) << 12) + nin*64
                              + ((((t << 1) | (lc >> 3)) ^ (nin & 7)) << 3) + (lc & 7);
                Kb[off] = f2bf(acc[t][r]);
            }
    } else {
        // V tile: tile=R>>6; off = d*64 + ((nin>>3)^(d&7))*8 + (nin&7)
#pragma unroll
        for (int t = 0; t < 4; ++t)
#pragma unroll
            for (int r = 0; r < 4; ++r){
                const int R = rloc + quad*4 + r;
                const int nin = R & 63;
                const int d = t*16 + lc;
                const int off = ((R >> 6) << 12) + d*64
                              + (((nin >> 3) ^ (lc & 7)) << 3) + (nin & 7);
                Vt[off] = f2bf(acc[t][r]);
            }
    }
}

// ---------------- Attention: block = (b, 64-row q-block j, k-chunk c).
// 4 waves share double-buffered global_load_lds-staged K/V tiles. (unchanged)
template<int SH>
__global__ __launch_bounds__(256)
void attn_part(const short* __restrict__ Qb, const short* __restrict__ Kb,
               const short* __restrict__ Vt, const unsigned char* __restrict__ pad,
               const int* __restrict__ mflag, float* __restrict__ out,
               float* __restrict__ Lp, short* __restrict__ Op)
{
    constexpr int M   = 1 << SH;
    constexpr int NG  = 32 / M;
    constexpr int UPB = M * NG * (NG + 1) / 2;
    constexpr int PPB = UPB - M;

    __shared__ short sK[2][4096];
    __shared__ short sV[2][4096];
    __shared__ short sP[4][16][80];

    const int tid = threadIdx.x, lane = tid & 63, lc = lane & 15, quad = lane >> 4, w = tid >> 6;
    const int unit = blockIdx.x;
    const int b = unit / UPB;
    const int rem = unit - b * UPB;
    int a = 0;
    while (rem >= (M * (a + 1) * (a + 2)) / 2) ++a;
    const int u = rem - M * a * (a + 1) / 2;
    const int C = a + 1;
    const int r = u / C, c = u - r * C;
    const int j = a * M + r;
    const int q0 = j * 64;

    const bool causal = (mflag[0] != 0);
    const int T = causal ? (j + 1) : 32;
    const int qq = (T + C - 1) / C;
    const int t0 = c * qq;
    const int t1 = min(t0 + qq, T);
    const int tb = b * 32;
    const unsigned char* padb = pad + (size_t)b * NN;

    const short* qrow = Qb + ((size_t)b * NN + q0 + w*16 + lc) * HD;
    const short8 qf0 = *(const short8*)(qrow + quad * 8);
    const short8 qf1 = *(const short8*)(qrow + 32 + quad * 8);

    f32x4 o[4];
#pragma unroll
    for (int t = 0; t < 4; ++t)
#pragma unroll
        for (int rr = 0; rr < 4; ++rr) o[t][rr] = 0.f;
    float lacc = 0.f;

    {
        const short* gk = Kb + ((size_t)(tb + t0) << 12) + w*1024 + lane*8;
        const short* gv = Vt + ((size_t)(tb + t0) << 12) + w*1024 + lane*8;
        short* lk = &sK[0][w*1024 + lane*8];
        short* lv = &sV[0][w*1024 + lane*8];
        gl16(gk, lk); gl16(gk + 512, lk + 512);
        gl16(gv, lv); gl16(gv + 512, lv + 512);
    }

    int buf = 0;
    const int sw = lc & 7;
    for (int kt = t0; kt < t1; ++kt, buf ^= 1){
        __syncthreads();
        if (kt + 1 < t1){
            const short* gk = Kb + ((size_t)(tb + kt + 1) << 12) + w*1024 + lane*8;
            const short* gv = Vt + ((size_t)(tb + kt + 1) << 12) + w*1024 + lane*8;
            short* lk = &sK[buf ^ 1][w*1024 + lane*8];
            short* lv = &sV[buf ^ 1][w*1024 + lane*8];
            gl16(gk, lk); gl16(gk + 512, lk + 512);
            gl16(gv, lv); gl16(gv + 512, lv + 512);
        }
        const int k0 = kt * 64;
        short8 kf0[4], kf1[4], vf0[4], vf1[4];
#pragma unroll
        for (int t = 0; t < 4; ++t){
            const int row = (t*16 + lc) * 64;
            kf0[t] = *(const short8*)&sK[buf][row + ((quad ^ sw) << 3)];
            kf1[t] = *(const short8*)&sK[buf][row + (((quad + 4) ^ sw) << 3)];
            vf0[t] = *(const short8*)&sV[buf][row + ((quad ^ sw) << 3)];
            vf1[t] = *(const short8*)&sV[buf][row + (((quad + 4) ^ sw) << 3)];
        }
        f32x4 st[4];
#pragma unroll
        for (int t = 0; t < 4; ++t){
#pragma unroll
            for (int rr = 0; rr < 4; ++rr) st[t][rr] = 0.f;
            st[t] = __builtin_amdgcn_mfma_f32_16x16x32_bf16(kf0[t], qf0, st[t], 0,0,0);
            st[t] = __builtin_amdgcn_mfma_f32_16x16x32_bf16(kf1[t], qf1, st[t], 0,0,0);
        }
        const bool dg = causal && (kt == j);
        const int thr = q0 + w*16 + lc - k0;
#pragma unroll
        for (int t = 0; t < 4; ++t){
            uchar4 pb = *(const uchar4*)(padb + k0 + t*16 + quad*4);
            float e[4];
#pragma unroll
            for (int rr = 0; rr < 4; ++rr){
                float v = st[t][rr];
                const unsigned char pr = (rr==0)?pb.x:(rr==1)?pb.y:(rr==2)?pb.z:pb.w;
                const int nloc = t*16 + quad*4 + rr;
                if (pr || (dg && nloc > thr)) v = -INFINITY;
                e[rr] = exp2f(v);
                lacc += e[rr];
            }
            union { short4v s4; unsigned uu[2]; } pk;
            pk.uu[0] = pkbf(e[0], e[1]);
            pk.uu[1] = pkbf(e[2], e[3]);
            *(short4v*)&sP[w][lc][t*16 + quad*4] = pk.s4;
        }
        const short8 pf0 = *(const short8*)&sP[w][lc][quad*8];
        const short8 pf1 = *(const short8*)&sP[w][lc][32 + quad*8];
#pragma unroll
        for (int t = 0; t < 4; ++t){
            o[t] = __builtin_amdgcn_mfma_f32_16x16x32_bf16(pf0, vf0[t], o[t], 0,0,0);
            o[t] = __builtin_amdgcn_mfma_f32_16x16x32_bf16(pf1, vf1[t], o[t], 0,0,0);
        }
    }

    lacc += __shfl_xor(lacc, 16);
    lacc += __shfl_xor(lacc, 32);

    if (C == 1){
        float linv[4];
#pragma unroll
        for (int rr = 0; rr < 4; ++rr) linv[rr] = 1.f / __shfl(lacc, quad*4 + rr);
#pragma unroll
        for (int rr = 0; rr < 4; ++rr){
            float* orow = out + ((size_t)b*NN + q0 + w*16 + quad*4 + rr)*HD;
#pragma unroll
            for (int t = 0; t < 4; ++t) orow[t*16 + lc] = o[t][rr] * linv[rr];
        }
    } else {
        const int pu = b*PPB + (M*a*(a+1)/2 - M) + r*C + c;
        short* op = Op + (size_t)pu * 4096;
#pragma unroll
        for (int t = 0; t < 4; ++t)
#pragma unroll
            for (int rr = 0; rr < 4; ++rr)
                op[(w*16 + quad*4 + rr)*64 + t*16 + lc] = f2bf(o[t][rr]);
        if (lane < 16) Lp[pu*64 + w*16 + lane] = lacc;
    }
}

// ---------------- Combine: one thread per output element.
// grid = BB * NSTR * 16 blocks; block = 256 thr = 4 rows x 64 lanes.
template<int SH>
__global__ __launch_bounds__(256)
void attn_combine(const float* __restrict__ Lp, const short* __restrict__ Op,
                  float* __restrict__ out)
{
    constexpr int M    = 1 << SH;
    constexpr int UPB  = M * (32/M) * (32/M + 1) / 2;
    constexpr int PPB  = UPB - M;
    constexpr int NSTR = 32 - M;
    const int tid = threadIdx.x, lane = tid & 63;
    const int unit = blockIdx.x;
    const int per_b = NSTR * 16;
    const int b = unit / per_b;
    const int rem = unit - b * per_b;
    const int j = M + (rem >> 4);
    const int row = (rem & 15) * 4 + (tid >> 6);
    const int a = j >> SH;
    const int C = a + 1;
    const int r = j - a * M;
    const int pu0 = b*PPB + (M*a*(a+1)/2 - M) + r*C;

    float l = 0.f, acc = 0.f;
    for (int cc = 0; cc < C; ++cc){
        l   += Lp[(pu0 + cc)*64 + row];
        acc += bf2f(Op[(size_t)(pu0 + cc)*4096 + row*64 + lane]);
    }
    out[((size_t)b*NN + j*64 + row)*HD + lane] = acc / l;
}

extern "C" void kernel_launch(void* const* d_in, const int* in_sizes, int n_in,
                              void* d_out, int out_size, void* d_ws, size_t ws_size,
                              hipStream_t stream) {
    const float* key_in   = (const float*)d_in[0];
    const float* query_in = (const float*)d_in[1];
    const float* value_in = (const float*)d_in[2];
    const unsigned char* pad = (const unsigned char*)d_in[3];
    const int* mflag      = (const int*)d_in[4];
    const float* Wk       = (const float*)d_in[5];
    // W_query / W_value unused — reference applies W_key to Q, K and V.

    short* Qb = (short*)d_ws;                    // 2 MiB (pre-scaled by QSCALE)
    short* Kb = Qb + (size_t)MROWS*HD;           // 2 MiB, swizzled tiles
    short* Vt = Kb + (size_t)MROWS*HD;           // 2 MiB, swizzled tiles [d][n]
    short* Wtf = Vt + (size_t)MROWS*HD;          // 64 KiB, frag order
    float* Lp = (float*)(Wtf + D_EMB*HD);

    wt_kernel<<<8, 256, 0, stream>>>(Wk, Wtf);
    proj_kernel<<<768, 256, 0, stream>>>(query_in, key_in, value_in, Wtf, Qb, Kb, Vt);

    if (ws_size >= (size_t)15818752){
        // SH=2: 1152 part-blocks, <=4 tiles each; Lp 1120*64 f32, Op 1120*4096 bf16
        short* Op = (short*)(Lp + 1120*64);
        attn_part<2><<<1152, 256, 0, stream>>>(Qb, Kb, Vt, pad, mflag, (float*)d_out, Lp, Op);
        attn_combine<2><<<BB*28*16, 256, 0, stream>>>(Lp, Op, (float*)d_out);
    } else {
        // SH=3: 640 part-blocks, <=8 tiles each; 11.2 MB total (proven fit)
        short* Op = (short*)(Lp + 576*64);
        attn_part<3><<<640, 256, 0, stream>>>(Qb, Kb, Vt, pad, mflag, (float*)d_out, Lp, Op);
        attn_combine<3><<<BB*24*16, 256, 0, stream>>>(Lp, Op, (float*)d_out);
    }
}

// Round 8
// 166.253 us; speedup vs baseline: 2.5869x; 1.0392x over previous
//
#include <hip/hip_runtime.h>
#include <hip/hip_bf16.h>
#include <math.h>

#define D_EMB 512
#define HD 64
#define BB 8
#define NN 2048
#define MROWS (BB*NN)   // 16384

typedef short short8  __attribute__((ext_vector_type(8)));
typedef short short4v __attribute__((ext_vector_type(4)));
typedef float f32x4   __attribute__((ext_vector_type(4)));

// scale(1/sqrt(512)) * log2(e): folded into Qb so P = exp2(S') directly
#define QSCALE 0.063758708f

__device__ __forceinline__ short f2bf(float x){
    unsigned u = __float_as_uint(x);
    unsigned r = (u + 0x7fffu + ((u >> 16) & 1u)) >> 16;
    return (short)r;
}
__device__ __forceinline__ float bf2f(short b){
    return __uint_as_float(((unsigned)(unsigned short)b) << 16);
}
__device__ __forceinline__ unsigned pkbf(float a, float b){
    __hip_bfloat162 h = __float22bfloat162_rn(make_float2(a, b));
    unsigned u; __builtin_memcpy(&u, &h, 4); return u;
}
// async global->LDS, 16B per lane (global_load_lds_dwordx4)
__device__ __forceinline__ void gl16(const short* g, short* l){
    __builtin_amdgcn_global_load_lds(
        (const __attribute__((address_space(1))) unsigned*)g,
        (__attribute__((address_space(3))) unsigned*)l, 16, 0, 0);
}

// ---------------- Wtf: W[k][n] f32 -> bf16 in MFMA B-frag order
// off = ((c16*4 + t)*64 + lane)*8 + j  with c16=k>>5, t=n>>4,
// lane=((k>>3)&3)*16 + (n&15), j=k&7
__global__ __launch_bounds__(256)
void wt_kernel(const float* __restrict__ W, short* __restrict__ Wtf){
    for (int idx = blockIdx.x * 256 + threadIdx.x; idx < D_EMB*HD; idx += 8*256){
        int k = idx >> 6, n = idx & 63;
        int off = (((k >> 5)*4 + (n >> 4))*64 + ((k >> 3) & 3)*16 + (n & 15))*8 + (k & 7);
        Wtf[off] = f2bf(W[idx]);
    }
}

// ---------------- Projection. 16 rows/wave, MFMA, 4-deep X prefetch.
// No LDS: B-frags are contiguous 16B global loads from frag-ordered Wtf
// (64 KB table, L1/L2-resident after first touch — avoids the 48 MB HBM
// re-fetch the per-block LDS staging caused in R7, and frees LDS for
// occupancy). launch_bounds(256,4): <=128 VGPR, 16 waves/CU.
__global__ __launch_bounds__(256, 4)
void proj_kernel(const float* __restrict__ Xq, const float* __restrict__ Xk,
                 const float* __restrict__ Xv, const short* __restrict__ Wtf,
                 short* __restrict__ Qb, short* __restrict__ Kb,
                 short* __restrict__ Vt)
{
    const int tid = threadIdx.x;
    const int lane = tid & 63;
    const int lc = lane & 15, quad = lane >> 4;
    const int wid = blockIdx.x * 4 + (tid >> 6);
    const int m0 = wid * 16;
    const int tensor = m0 >> 14;             // 0=Q 1=K 2=V
    const int rloc = m0 & (MROWS - 1);
    const float* X = (tensor == 0) ? Xq : (tensor == 1 ? Xk : Xv);
    const float* xbase = X + (size_t)(rloc + lc)*D_EMB + quad*8;

    f32x4 acc[4];
#pragma unroll
    for (int t = 0; t < 4; ++t)
#pragma unroll
        for (int r = 0; r < 4; ++r) acc[t][r] = 0.f;

    float4 xa[4][2];
#pragma unroll
    for (int p = 0; p < 4; ++p){
        xa[p][0] = *(const float4*)(xbase + p*32);
        xa[p][1] = *(const float4*)(xbase + p*32 + 4);
    }
#pragma unroll
    for (int c16 = 0; c16 < 16; ++c16){
        float4 f0 = xa[c16 & 3][0], f1 = xa[c16 & 3][1];
        if (c16 < 12){
            xa[c16 & 3][0] = *(const float4*)(xbase + (c16+4)*32);
            xa[c16 & 3][1] = *(const float4*)(xbase + (c16+4)*32 + 4);
        }
        union { short8 s8; unsigned u[4]; } a;
        a.u[0] = pkbf(f0.x, f0.y); a.u[1] = pkbf(f0.z, f0.w);
        a.u[2] = pkbf(f1.x, f1.y); a.u[3] = pkbf(f1.z, f1.w);
#pragma unroll
        for (int t = 0; t < 4; ++t){
            short8 bf = *(const short8*)(Wtf + (size_t)(((c16*4 + t)*64 + lane)*8));
            acc[t] = __builtin_amdgcn_mfma_f32_16x16x32_bf16(a.s8, bf, acc[t], 0,0,0);
        }
    }

    if (tensor == 0){
#pragma unroll
        for (int t = 0; t < 4; ++t)
#pragma unroll
            for (int r = 0; r < 4; ++r)
                Qb[(size_t)(rloc + quad*4 + r)*HD + t*16 + lc] = f2bf(acc[t][r] * QSCALE);
    } else if (tensor == 1){
        // K tile: tile=R>>6; off = nin*64 + ((d>>3)^(nin&7))*8 + (d&7)
#pragma unroll
        for (int t = 0; t < 4; ++t)
#pragma unroll
            for (int r = 0; r < 4; ++r){
                const int R = rloc + quad*4 + r;
                const int nin = R & 63;
                const int off = ((R >> 6) << 12) + nin*64
                              + ((((t << 1) | (lc >> 3)) ^ (nin & 7)) << 3) + (lc & 7);
                Kb[off] = f2bf(acc[t][r]);
            }
    } else {
        // V tile: tile=R>>6; off = d*64 + ((nin>>3)^(d&7))*8 + (nin&7)
#pragma unroll
        for (int t = 0; t < 4; ++t)
#pragma unroll
            for (int r = 0; r < 4; ++r){
                const int R = rloc + quad*4 + r;
                const int nin = R & 63;
                const int d = t*16 + lc;
                const int off = ((R >> 6) << 12) + d*64
                              + (((nin >> 3) ^ (lc & 7)) << 3) + (nin & 7);
                Vt[off] = f2bf(acc[t][r]);
            }
    }
}

// ---------------- Attention: block = (b, 64-row q-block j, k-chunk c).
// 4 waves share double-buffered global_load_lds-staged K/V tiles. (unchanged)
template<int SH>
__global__ __launch_bounds__(256)
void attn_part(const short* __restrict__ Qb, const short* __restrict__ Kb,
               const short* __restrict__ Vt, const unsigned char* __restrict__ pad,
               const int* __restrict__ mflag, float* __restrict__ out,
               float* __restrict__ Lp, short* __restrict__ Op)
{
    constexpr int M   = 1 << SH;
    constexpr int NG  = 32 / M;
    constexpr int UPB = M * NG * (NG + 1) / 2;
    constexpr int PPB = UPB - M;

    __shared__ short sK[2][4096];
    __shared__ short sV[2][4096];
    __shared__ short sP[4][16][80];

    const int tid = threadIdx.x, lane = tid & 63, lc = lane & 15, quad = lane >> 4, w = tid >> 6;
    const int unit = blockIdx.x;
    const int b = unit / UPB;
    const int rem = unit - b * UPB;
    int a = 0;
    while (rem >= (M * (a + 1) * (a + 2)) / 2) ++a;
    const int u = rem - M * a * (a + 1) / 2;
    const int C = a + 1;
    const int r = u / C, c = u - r * C;
    const int j = a * M + r;
    const int q0 = j * 64;

    const bool causal = (mflag[0] != 0);
    const int T = causal ? (j + 1) : 32;
    const int qq = (T + C - 1) / C;
    const int t0 = c * qq;
    const int t1 = min(t0 + qq, T);
    const int tb = b * 32;
    const unsigned char* padb = pad + (size_t)b * NN;

    const short* qrow = Qb + ((size_t)b * NN + q0 + w*16 + lc) * HD;
    const short8 qf0 = *(const short8*)(qrow + quad * 8);
    const short8 qf1 = *(const short8*)(qrow + 32 + quad * 8);

    f32x4 o[4];
#pragma unroll
    for (int t = 0; t < 4; ++t)
#pragma unroll
        for (int rr = 0; rr < 4; ++rr) o[t][rr] = 0.f;
    float lacc = 0.f;

    {
        const short* gk = Kb + ((size_t)(tb + t0) << 12) + w*1024 + lane*8;
        const short* gv = Vt + ((size_t)(tb + t0) << 12) + w*1024 + lane*8;
        short* lk = &sK[0][w*1024 + lane*8];
        short* lv = &sV[0][w*1024 + lane*8];
        gl16(gk, lk); gl16(gk + 512, lk + 512);
        gl16(gv, lv); gl16(gv + 512, lv + 512);
    }

    int buf = 0;
    const int sw = lc & 7;
    for (int kt = t0; kt < t1; ++kt, buf ^= 1){
        __syncthreads();
        if (kt + 1 < t1){
            const short* gk = Kb + ((size_t)(tb + kt + 1) << 12) + w*1024 + lane*8;
            const short* gv = Vt + ((size_t)(tb + kt + 1) << 12) + w*1024 + lane*8;
            short* lk = &sK[buf ^ 1][w*1024 + lane*8];
            short* lv = &sV[buf ^ 1][w*1024 + lane*8];
            gl16(gk, lk); gl16(gk + 512, lk + 512);
            gl16(gv, lv); gl16(gv + 512, lv + 512);
        }
        const int k0 = kt * 64;
        short8 kf0[4], kf1[4], vf0[4], vf1[4];
#pragma unroll
        for (int t = 0; t < 4; ++t){
            const int row = (t*16 + lc) * 64;
            kf0[t] = *(const short8*)&sK[buf][row + ((quad ^ sw) << 3)];
            kf1[t] = *(const short8*)&sK[buf][row + (((quad + 4) ^ sw) << 3)];
            vf0[t] = *(const short8*)&sV[buf][row + ((quad ^ sw) << 3)];
            vf1[t] = *(const short8*)&sV[buf][row + (((quad + 4) ^ sw) << 3)];
        }
        f32x4 st[4];
#pragma unroll
        for (int t = 0; t < 4; ++t){
#pragma unroll
            for (int rr = 0; rr < 4; ++rr) st[t][rr] = 0.f;
            st[t] = __builtin_amdgcn_mfma_f32_16x16x32_bf16(kf0[t], qf0, st[t], 0,0,0);
            st[t] = __builtin_amdgcn_mfma_f32_16x16x32_bf16(kf1[t], qf1, st[t], 0,0,0);
        }
        const bool dg = causal && (kt == j);
        const int thr = q0 + w*16 + lc - k0;
#pragma unroll
        for (int t = 0; t < 4; ++t){
            uchar4 pb = *(const uchar4*)(padb + k0 + t*16 + quad*4);
            float e[4];
#pragma unroll
            for (int rr = 0; rr < 4; ++rr){
                float v = st[t][rr];
                const unsigned char pr = (rr==0)?pb.x:(rr==1)?pb.y:(rr==2)?pb.z:pb.w;
                const int nloc = t*16 + quad*4 + rr;
                if (pr || (dg && nloc > thr)) v = -INFINITY;
                e[rr] = exp2f(v);
                lacc += e[rr];
            }
            union { short4v s4; unsigned uu[2]; } pk;
            pk.uu[0] = pkbf(e[0], e[1]);
            pk.uu[1] = pkbf(e[2], e[3]);
            *(short4v*)&sP[w][lc][t*16 + quad*4] = pk.s4;
        }
        const short8 pf0 = *(const short8*)&sP[w][lc][quad*8];
        const short8 pf1 = *(const short8*)&sP[w][lc][32 + quad*8];
#pragma unroll
        for (int t = 0; t < 4; ++t){
            o[t] = __builtin_amdgcn_mfma_f32_16x16x32_bf16(pf0, vf0[t], o[t], 0,0,0);
            o[t] = __builtin_amdgcn_mfma_f32_16x16x32_bf16(pf1, vf1[t], o[t], 0,0,0);
        }
    }

    lacc += __shfl_xor(lacc, 16);
    lacc += __shfl_xor(lacc, 32);

    if (C == 1){
        float linv[4];
#pragma unroll
        for (int rr = 0; rr < 4; ++rr) linv[rr] = 1.f / __shfl(lacc, quad*4 + rr);
#pragma unroll
        for (int rr = 0; rr < 4; ++rr){
            float* orow = out + ((size_t)b*NN + q0 + w*16 + quad*4 + rr)*HD;
#pragma unroll
            for (int t = 0; t < 4; ++t) orow[t*16 + lc] = o[t][rr] * linv[rr];
        }
    } else {
        const int pu = b*PPB + (M*a*(a+1)/2 - M) + r*C + c;
        short* op = Op + (size_t)pu * 4096;
#pragma unroll
        for (int t = 0; t < 4; ++t)
#pragma unroll
            for (int rr = 0; rr < 4; ++rr)
                op[(w*16 + quad*4 + rr)*64 + t*16 + lc] = f2bf(o[t][rr]);
        if (lane < 16) Lp[pu*64 + w*16 + lane] = lacc;
    }
}

// ---------------- Combine: one thread per output element.
template<int SH>
__global__ __launch_bounds__(256)
void attn_combine(const float* __restrict__ Lp, const short* __restrict__ Op,
                  float* __restrict__ out)
{
    constexpr int M    = 1 << SH;
    constexpr int UPB  = M * (32/M) * (32/M + 1) / 2;
    constexpr int PPB  = UPB - M;
    constexpr int NSTR = 32 - M;
    const int tid = threadIdx.x, lane = tid & 63;
    const int unit = blockIdx.x;
    const int per_b = NSTR * 16;
    const int b = unit / per_b;
    const int rem = unit - b * per_b;
    const int j = M + (rem >> 4);
    const int row = (rem & 15) * 4 + (tid >> 6);
    const int a = j >> SH;
    const int C = a + 1;
    const int r = j - a * M;
    const int pu0 = b*PPB + (M*a*(a+1)/2 - M) + r*C;

    float l = 0.f, acc = 0.f;
    for (int cc = 0; cc < C; ++cc){
        l   += Lp[(pu0 + cc)*64 + row];
        acc += bf2f(Op[(size_t)(pu0 + cc)*4096 + row*64 + lane]);
    }
    out[((size_t)b*NN + j*64 + row)*HD + lane] = acc / l;
}

extern "C" void kernel_launch(void* const* d_in, const int* in_sizes, int n_in,
                              void* d_out, int out_size, void* d_ws, size_t ws_size,
                              hipStream_t stream) {
    const float* key_in   = (const float*)d_in[0];
    const float* query_in = (const float*)d_in[1];
    const float* value_in = (const float*)d_in[2];
    const unsigned char* pad = (const unsigned char*)d_in[3];
    const int* mflag      = (const int*)d_in[4];
    const float* Wk       = (const float*)d_in[5];
    // W_query / W_value unused — reference applies W_key to Q, K and V.

    short* Qb = (short*)d_ws;                    // 2 MiB (pre-scaled by QSCALE)
    short* Kb = Qb + (size_t)MROWS*HD;           // 2 MiB, swizzled tiles
    short* Vt = Kb + (size_t)MROWS*HD;           // 2 MiB, swizzled tiles [d][n]
    short* Wtf = Vt + (size_t)MROWS*HD;          // 64 KiB, frag order
    float* Lp = (float*)(Wtf + D_EMB*HD);

    wt_kernel<<<8, 256, 0, stream>>>(Wk, Wtf);
    proj_kernel<<<768, 256, 0, stream>>>(query_in, key_in, value_in, Wtf, Qb, Kb, Vt);

    if (ws_size >= (size_t)15818752){
        // SH=2: 1152 part-blocks, <=4 tiles each; Lp 1120*64 f32, Op 1120*4096 bf16
        short* Op = (short*)(Lp + 1120*64);
        attn_part<2><<<1152, 256, 0, stream>>>(Qb, Kb, Vt, pad, mflag, (float*)d_out, Lp, Op);
        attn_combine<2><<<BB*28*16, 256, 0, stream>>>(Lp, Op, (float*)d_out);
    } else {
        // SH=3: 640 part-blocks, <=8 tiles each; 11.2 MB total (proven fit)
        short* Op = (short*)(Lp + 576*64);
        attn_part<3><<<640, 256, 0, stream>>>(Qb, Kb, Vt, pad, mflag, (float*)d_out, Lp, Op);
        attn_combine<3><<<BB*24*16, 256, 0, stream>>>(Lp, Op, (float*)d_out);
    }
}